// Round 9
// baseline (267.283 us; speedup 1.0000x reference)
//
#include <hip/hip_runtime.h>
#include <hip/hip_bf16.h>

// DecoderLayer cross-attention, MI355X/gfx950. Round 12.
// B=4, Sq=2048, Skv=4096, D=512. fp32 in/out, bf16 MFMA internally.
// R12 changes vs R11 (flat) / R10 (best=232):
//  - cvt/proj/reduce REVERTED to R10 exactly (R11's fp32-staged proj was a wash).
//  - attn: 4 waves (256 thr) at 1 block/CU -> 1 wave/SIMD -> full unified VGPR+AGPR
//    budget (R8's 2x B-frag-reuse died only because 512-thr blocks cap at 256 regs).
//    Each wave: QK quadrant 32q x 32kv (af[2][16]=128 regs, each Kt read feeds 2 MFMA
//    -> Kt reads 256->128/tile) + PV strip 64q x 128e (oacc[4][8]=128 -> AGPRs).
//    LDS port ~4,300 -> ~2,300 cyc/tile; MFMA (2,483) becomes the binding pipe.
// ws layout:
//   Qb  bf16 [8192][512]          @ 0           (8,388,608)
//   Kb  bf16 [16384][512]         @ 8,388,608   (16,777,216)
//   Vtg bf16 [4][128][512][32]    @ 25,165,824  (16,777,216)   (t-tiled)
//   region B @ 41,943,040:
//     phase1: xb 8.4M | encb @+8.4M 16.8M | wqb/wkb/wvb @+25.2M 0.5M each
//     phase2: Op f32 [2][8192][512] | lp f32 [2][8192]  (need 75,563,008 B)

typedef __bf16 bf16;
typedef __attribute__((ext_vector_type(8))) __bf16 bf16x8;
typedef __attribute__((ext_vector_type(4))) float f32x4;

#define DM 512

__device__ __forceinline__ void gload_lds16(const bf16* g, bf16* l)
{
    __builtin_amdgcn_global_load_lds(
        (const __attribute__((address_space(1))) void*)g,
        (__attribute__((address_space(3))) void*)l, 16, 0, 0);
}

// ---------------- fp32 -> bf16 convert prepass (single launch, 5 regions) -----------------
__global__ __launch_bounds__(256) void cvt_all_kernel(
    const float* __restrict__ x,   bf16* __restrict__ xb,
    const float* __restrict__ enc, bf16* __restrict__ encb,
    const float* __restrict__ wq,  bf16* __restrict__ wqb,
    const float* __restrict__ wk,  bf16* __restrict__ wkb,
    const float* __restrict__ wv,  bf16* __restrict__ wvb)
{
    int g = blockIdx.x * 256 + threadIdx.x;
    const float* src; bf16* dst;
    if (g < 524288)       { src = x;   dst = xb; }
    else if (g < 1572864) { g -= 524288;  src = enc; dst = encb; }
    else if (g < 1605632) { g -= 1572864; src = wq;  dst = wqb; }
    else if (g < 1638400) { g -= 1605632; src = wk;  dst = wkb; }
    else                  { g -= 1638400; src = wv;  dst = wvb; }
    const float4 f0 = *reinterpret_cast<const float4*>(src + (size_t)g * 8);
    const float4 f1 = *reinterpret_cast<const float4*>(src + (size_t)g * 8 + 4);
    bf16x8 v;
    v[0]=(bf16)f0.x; v[1]=(bf16)f0.y; v[2]=(bf16)f0.z; v[3]=(bf16)f0.w;
    v[4]=(bf16)f1.x; v[5]=(bf16)f1.y; v[6]=(bf16)f1.z; v[7]=(bf16)f1.w;
    *reinterpret_cast<bf16x8*>(dst + (size_t)g * 8) = v;
}

// ---------------- Projection GEMMs, m97 structure (R10-identical) --------------------------
// 128x128 tile, BK=32, 256 threads (4 waves 2x2), dbuf LDS via global_load_lds (1KB/instr).
// KV=false: Q row-major. KV=true: K row-major + V t-tiled Vtg[b][t>>5][e][t&31].
template<bool KV>
__global__ __launch_bounds__(256, 2) void proj_kernel(const bf16* __restrict__ A,
    const bf16* __restrict__ W0, const float* __restrict__ b0, bf16* __restrict__ out0,
    const bf16* __restrict__ W1, const float* __restrict__ b1, bf16* __restrict__ out1)
{
    __shared__ __align__(16) bf16 As[2][128][32];
    __shared__ __align__(16) bf16 W0s[2][128][32];
    __shared__ __align__(16) bf16 W1s[2][128][32];   // eliminated by compiler when !KV

    const int tid  = threadIdx.x;
    const int w    = tid >> 6, lane = tid & 63, quad = lane >> 4, l15 = lane & 15;
    const int wr   = w >> 1, wc = w & 1;
    const int n0   = blockIdx.x * 128;
    const int m0   = blockIdx.y * 128;

    const int lrow = lane >> 2;
    const int scol = ((lane & 3) ^ (lrow & 3)) * 8;
    const bf16* aSrc  = A  + (size_t)(m0 + lrow) * DM + scol;
    const bf16* wSrc0 = W0 + (size_t)(n0 + lrow) * DM + scol;
    const bf16* wSrc1 = KV ? (W1 + (size_t)(n0 + lrow) * DM + scol) : nullptr;

    auto stage = [&](int p, int kk) {
#pragma unroll
        for (int j = 0; j < 2; j++) {
            const int seg = 2 * w + j;                  // 8 segments of 16 rows
            gload_lds16(aSrc  + (size_t)(16 * seg) * DM + kk, &As[p][16 * seg][0]);
            gload_lds16(wSrc0 + (size_t)(16 * seg) * DM + kk, &W0s[p][16 * seg][0]);
            if constexpr (KV)
                gload_lds16(wSrc1 + (size_t)(16 * seg) * DM + kk, &W1s[p][16 * seg][0]);
        }
    };

    f32x4 acc0[4][4] = {}, acc1[4][4] = {};
    const int sx = (l15 & 3);

    stage(0, 0);
    __syncthreads();

    for (int step = 0; step < 16; step++) {
        const int p = step & 1;
        if (step < 15) stage(p ^ 1, (step + 1) * 32);

        bf16x8 af[4];
#pragma unroll
        for (int mt = 0; mt < 4; mt++)
            af[mt] = *reinterpret_cast<const bf16x8*>(
                &As[p][64*wr + 16*mt + l15][(quad ^ sx) * 8]);
#pragma unroll
        for (int nt = 0; nt < 4; nt++) {
            bf16x8 w0f = *reinterpret_cast<const bf16x8*>(
                &W0s[p][64*wc + 16*nt + l15][(quad ^ sx) * 8]);
#pragma unroll
            for (int mt = 0; mt < 4; mt++)
                acc0[mt][nt] = __builtin_amdgcn_mfma_f32_16x16x32_bf16(af[mt], w0f, acc0[mt][nt], 0, 0, 0);
            if constexpr (KV) {
                bf16x8 w1f = *reinterpret_cast<const bf16x8*>(
                    &W1s[p][64*wc + 16*nt + l15][(quad ^ sx) * 8]);
#pragma unroll
                for (int mt = 0; mt < 4; mt++)
                    acc1[mt][nt] = __builtin_amdgcn_mfma_f32_16x16x32_bf16(af[mt], w1f, acc1[mt][nt], 0, 0, 0);
            }
        }
        __syncthreads();
    }

#pragma unroll
    for (int mt = 0; mt < 4; mt++)
#pragma unroll
        for (int nt = 0; nt < 4; nt++) {
            const int coll = 64*wc + 16*nt + l15;
            const int rowl = 64*wr + 16*mt + quad*4;
            {
                const float bv = b0[n0 + coll];
                f32x4 c = acc0[mt][nt];
#pragma unroll
                for (int r = 0; r < 4; r++)
                    out0[(size_t)(m0 + rowl + r) * DM + n0 + coll] = (bf16)(c[r] + bv);
            }
            if constexpr (KV) {
                const float bv = b1[n0 + coll];
                f32x4 c = acc1[mt][nt];
                const int gr = m0 + rowl;
                const int bidx = gr >> 12, t = gr & 4095;
                const int e = n0 + coll;
                union { uint2 u; bf16 h[4]; } pk;
#pragma unroll
                for (int r = 0; r < 4; r++) pk.h[r] = (bf16)(c[r] + bv);
                *reinterpret_cast<uint2*>(out1 +
                    ((((size_t)(bidx*128 + (t >> 5)) * DM + e) << 5) + (t & 31))) = pk.u;
            }
        }
}

// ---------------- Fused attention: 4 waves, 1 wave/SIMD, 2x B-frag reuse -------------------
// 256 threads / 4 waves, 1 block/CU, grid 256 = 1 round.
// QK: wave (qh=w>>1, kh=w&1) owns quadrant S[32qh..+32][32kh..+32]:
//     af[2][16] (128 VGPR), each Kt B-frag read feeds 2 MFMAs -> 128 Kt reads/tile.
// PV: wave w owns O[64 q][128 e cols 128w..]: oacc[4][8] (128 regs -> AGPR file).
// vf (both ks) issued BEFORE K-DMA so PV's counted vmcnt leaves the DMA in flight (R9).
__global__ __launch_bounds__(256, 1) void attn_kernel(const bf16* __restrict__ Qb,
                                                      const bf16* __restrict__ Kb,
                                                      const bf16* __restrict__ Vtg,
                                                      float* __restrict__ Op,
                                                      float* __restrict__ lp)
{
    __shared__ __align__(16) bf16 Kt[2][64][512];   // 131,072 B; 4-bit XOR swizzle (src-side)
    __shared__ __align__(16) bf16 Ps[64][80];       //  10,240 B; 40 dw stride
    __shared__ float lred[64];

    const int tid  = threadIdx.x;
    const int w    = tid >> 6, lane = tid & 63, quad = lane >> 4, l15 = lane & 15;
    const int qh   = w >> 1;                 // QK q-row half 0..1
    const int kh   = w & 1;                  // QK kv-col half 0..1

    // XCD-swizzle: 8 (b,z) combos map 1:1 onto 8 XCDs.
    const int id = blockIdx.x;               // 256 blocks
    const int combo = id & 7, qblk = id >> 3;
    const int b = combo & 3, z = combo >> 2;
    const int q0 = qblk * 64;
    const int NT = 32, tb = z * 2048;        // 32 tiles of 64 kv rows

    // ---- Q A-fragments into registers: af[mt][k4], rows 32qh+16mt+l15 (128 VGPR) ----
    bf16x8 af[2][16];
#pragma unroll
    for (int mt = 0; mt < 2; mt++) {
        const bf16* qsrc = Qb + (size_t)(b*2048 + q0 + 32*qh + 16*mt + l15) * DM + quad*8;
#pragma unroll
        for (int k4 = 0; k4 < 16; k4++)
            af[mt][k4] = *reinterpret_cast<const bf16x8*>(qsrc + k4*32);
    }
    if (tid < 64) lred[tid] = 0.f;

    const bf16* kbase = Kb + (size_t)(b*4096 + tb) * DM;
    // ---- stage K tile 0 (1 contiguous 1KB row/instr; source lane 4-bit XOR) ----
#pragma unroll
    for (int i = 0; i < 16; i++) {
        const int row = w + 4*i;             // 16 rows per wave, covers 0..63
        gload_lds16(kbase + (size_t)row * DM + ((lane ^ (row & 15)) * 8), &Kt[0][row][0]);
    }
    __syncthreads();                          // drains DMA, publishes lred

    f32x4 oacc[4][8] = {};                    // -> AGPR file (unified budget, 1 wave/SIMD)
    float lsum[2][4] = {};
    const float kexp = 1.44269504088896f * 0.044194173824159216f;  // log2(e)/sqrt(512)
    const int sxor = l15 << 4;                // read-side 4-bit XOR (rows read have row&15==l15)

    for (int t = 0; t < NT; t++) {
        const int buf = t & 1;

        // V fragments (both ks) FIRST: oldest vmcnt -> PV waits leave K-DMA in flight
        bf16x8 vf[2][8];
#pragma unroll
        for (int ks = 0; ks < 2; ks++) {
            const size_t tblk = (size_t)(b*128 + z*64 + t*2 + ks) * DM;
#pragma unroll
            for (int nt = 0; nt < 8; nt++)
                vf[ks][nt] = *reinterpret_cast<const bf16x8*>(
                    Vtg + ((tblk + 128*w + 16*nt + l15) << 5) + quad*8);
        }

        // prefetch next K tile (stays in flight until end-of-tile __syncthreads)
        if (t + 1 < NT) {
            const bf16* ksrc = kbase + (size_t)(t + 1) * 64 * DM;
#pragma unroll
            for (int i = 0; i < 16; i++) {
                const int row = w + 4*i;
                gload_lds16(ksrc + (size_t)row * DM + ((lane ^ (row & 15)) * 8), &Kt[buf ^ 1][row][0]);
            }
        }

        // ---- QK: quadrant S[32qh..+32][32kh..+32]; each Kt read feeds 2 MFMAs ----
        f32x4 sacc[2][2] = {};
        const char* krow0 = (const char*)&Kt[buf][32*kh + l15][0];
        const char* krow1 = (const char*)&Kt[buf][32*kh + 16 + l15][0];
#pragma unroll
        for (int k4 = 0; k4 < 16; k4++) {
            const int off = (k4*64 + quad*16) ^ sxor;
            bf16x8 k0 = *reinterpret_cast<const bf16x8*>(krow0 + off);
            bf16x8 k1 = *reinterpret_cast<const bf16x8*>(krow1 + off);
#pragma unroll
            for (int mt = 0; mt < 2; mt++) {
                sacc[mt][0] = __builtin_amdgcn_mfma_f32_16x16x32_bf16(af[mt][k4], k0, sacc[mt][0], 0, 0, 0);
                sacc[mt][1] = __builtin_amdgcn_mfma_f32_16x16x32_bf16(af[mt][k4], k1, sacc[mt][1], 0, 0, 0);
            }
        }

        // exp -> Ps (C-layout -> A-layout), accumulate l
#pragma unroll
        for (int mt = 0; mt < 2; mt++)
#pragma unroll
            for (int ni = 0; ni < 2; ni++)
#pragma unroll
                for (int r = 0; r < 4; r++) {
                    const float p = exp2f(sacc[mt][ni][r] * kexp);
                    lsum[mt][r] += p;
                    Ps[32*qh + 16*mt + quad*4 + r][32*kh + 16*ni + l15] = (bf16)p;
                }

        // mid-tile barrier: lgkm-only (Ps is DS traffic; keep K-DMA in flight)
        asm volatile("s_waitcnt lgkmcnt(0)" ::: "memory");
        __builtin_amdgcn_s_barrier();
        __builtin_amdgcn_sched_barrier(0);

        // ---- PV: O[64][128w..+128] += P[64][64] * V[64][...], A LDS x B regs ----
#pragma unroll
        for (int ks = 0; ks < 2; ks++) {
#pragma unroll
            for (int mt = 0; mt < 4; mt++) {
                bf16x8 ap = *reinterpret_cast<const bf16x8*>(&Ps[16*mt + l15][ks*32 + quad*8]);
#pragma unroll
                for (int nt = 0; nt < 8; nt++)
                    oacc[mt][nt] = __builtin_amdgcn_mfma_f32_16x16x32_bf16(ap, vf[ks][nt], oacc[mt][nt], 0, 0, 0);
            }
        }
        __syncthreads();                      // protect Ps + publish K-DMA for next tile
    }

    // ---- epilogue: l reduction + O partial write ----
#pragma unroll
    for (int mt = 0; mt < 2; mt++)
#pragma unroll
        for (int r = 0; r < 4; r++)
            atomicAdd(&lred[32*qh + 16*mt + quad*4 + r], lsum[mt][r]);
    __syncthreads();

    if (tid < 64) lp[(size_t)z * 8192 + b * 2048 + q0 + tid] = lred[tid];
#pragma unroll
    for (int mt = 0; mt < 4; mt++)
#pragma unroll
        for (int r = 0; r < 4; r++) {
            const int row = 16*mt + quad*4 + r;
            float* obase = Op + ((size_t)z * 8192 + b * 2048 + q0 + row) * DM;
#pragma unroll
            for (int nt = 0; nt < 8; nt++)
                obase[128*w + 16*nt + l15] = oacc[mt][nt][r];
        }
}

// ---------------- Combine split partials: out = sum_z Op[z] / sum_z l[z] -------------------
__global__ __launch_bounds__(256) void reduce_kernel(const float* __restrict__ Op,
                                                     const float* __restrict__ lp,
                                                     float* __restrict__ out)
{
    const int g = blockIdx.x * 256 + threadIdx.x;    // 1,048,576 threads x float4
    const size_t e = (size_t)g * 4;
    const int row = g >> 7;
    float4 o = *reinterpret_cast<const float4*>(Op + e);
    float4 a = *reinterpret_cast<const float4*>(Op + 4194304 + e);
    const float l = lp[row] + lp[8192 + row];
    const float linv = 1.0f / l;
    o.x = (o.x + a.x) * linv;
    o.y = (o.y + a.y) * linv;
    o.z = (o.z + a.z) * linv;
    o.w = (o.w + a.w) * linv;
    *reinterpret_cast<float4*>(out + e) = o;
}

extern "C" void kernel_launch(void* const* d_in, const int* in_sizes, int n_in,
                              void* d_out, int out_size, void* d_ws, size_t ws_size,
                              hipStream_t stream)
{
    const float* x   = (const float*)d_in[0];
    const float* enc = (const float*)d_in[1];
    const float* wq  = (const float*)d_in[2];
    const float* bq  = (const float*)d_in[3];
    const float* wk  = (const float*)d_in[4];
    const float* bk  = (const float*)d_in[5];
    const float* wv  = (const float*)d_in[6];
    const float* bv  = (const float*)d_in[7];
    float* out = (float*)d_out;

    char* ws = (char*)d_ws;
    bf16*  Qb   = (bf16*)ws;
    bf16*  Kb   = (bf16*)(ws + 8388608);
    bf16*  Vtg  = (bf16*)(ws + 25165824);
    bf16*  xb   = (bf16*)(ws + 41943040);
    bf16*  encb = (bf16*)(ws + 50331648);
    bf16*  wqb  = (bf16*)(ws + 67108864);
    bf16*  wkb  = (bf16*)(ws + 67633152);
    bf16*  wvb  = (bf16*)(ws + 68157440);
    float* Op   = (float*)(ws + 41943040);          // overlaps xb/encb/w*b (phase 2)
    float* lp   = (float*)(ws + 41943040 + 2ull * 16777216);

    // prepass: fp32 -> bf16, single launch
    hipLaunchKernelGGL(cvt_all_kernel, dim3(6528), dim3(256), 0, stream,
                       x, xb, enc, encb, wq, wqb, wk, wkb, wv, wvb);

    // projections (m97-structure 128x128 tiles)
    hipLaunchKernelGGL((proj_kernel<false>), dim3(4, 64), dim3(256), 0, stream,
                       xb, wqb, bq, Qb, (const bf16*)nullptr, (const float*)nullptr, (bf16*)nullptr);
    hipLaunchKernelGGL((proj_kernel<true>),  dim3(4, 128), dim3(256), 0, stream,
                       encb, wkb, bk, Kb, wvb, bv, Vtg);

    // attention (256 blocks x 256 threads, 1 block/CU, 1 wave/SIMD) + combine
    hipLaunchKernelGGL(attn_kernel, dim3(256), dim3(256), 0, stream, Qb, Kb, Vtg, Op, lp);
    hipLaunchKernelGGL(reduce_kernel, dim3(4096), dim3(256), 0, stream, Op, lp, out);
}

// Round 10
// 248.912 us; speedup vs baseline: 1.0738x; 1.0738x over previous
//
#include <hip/hip_runtime.h>
#include <hip/hip_bf16.h>

// DecoderLayer cross-attention, MI355X/gfx950. Round 13.
// B=4, Sq=2048, Skv=4096, D=512. fp32 in/out, bf16 MFMA internally.
// R13 changes vs R12 (1-wave/SIMD regression: no TLP -> all latency exposed):
//  - attn geometry REVERTED to R9 (8 waves, 2/SIMD, af[16], 4x qb x 2x cb).
//  - attn: SINGLE-BARRIER PIPELINE: Ps double-buffered; iteration t does
//    {DMA K(t+1); issue vf(t-1); QK(t)+exp->Ps[t&1]; PV(t-1) from Ps[(t-1)&1]} then
//    ONE lgkm-only barrier. PV(t-1) MFMAs overlap QK(t)'s VALU/LDS windows.
//    DMA safety: vf issued AFTER DMA, vmcnt is FIFO -> PV's vf-wait implies DMA done;
//    t=0 (no PV) drains vmcnt(0) explicitly.
//  - cvt/proj/reduce byte-identical to R10 (best measured).
// ws layout:
//   Qb  bf16 [8192][512]          @ 0           (8,388,608)
//   Kb  bf16 [16384][512]         @ 8,388,608   (16,777,216)
//   Vtg bf16 [4][128][512][32]    @ 25,165,824  (16,777,216)   (t-tiled)
//   region B @ 41,943,040:
//     phase1: xb 8.4M | encb @+8.4M 16.8M | wqb/wkb/wvb @+25.2M 0.5M each
//     phase2: Op f32 [2][8192][512] | lp f32 [2][8192]  (need 75,563,008 B)

typedef __bf16 bf16;
typedef __attribute__((ext_vector_type(8))) __bf16 bf16x8;
typedef __attribute__((ext_vector_type(4))) float f32x4;

#define DM 512

__device__ __forceinline__ void gload_lds16(const bf16* g, bf16* l)
{
    __builtin_amdgcn_global_load_lds(
        (const __attribute__((address_space(1))) void*)g,
        (__attribute__((address_space(3))) void*)l, 16, 0, 0);
}

// ---------------- fp32 -> bf16 convert prepass (single launch, 5 regions) -----------------
__global__ __launch_bounds__(256) void cvt_all_kernel(
    const float* __restrict__ x,   bf16* __restrict__ xb,
    const float* __restrict__ enc, bf16* __restrict__ encb,
    const float* __restrict__ wq,  bf16* __restrict__ wqb,
    const float* __restrict__ wk,  bf16* __restrict__ wkb,
    const float* __restrict__ wv,  bf16* __restrict__ wvb)
{
    int g = blockIdx.x * 256 + threadIdx.x;
    const float* src; bf16* dst;
    if (g < 524288)       { src = x;   dst = xb; }
    else if (g < 1572864) { g -= 524288;  src = enc; dst = encb; }
    else if (g < 1605632) { g -= 1572864; src = wq;  dst = wqb; }
    else if (g < 1638400) { g -= 1605632; src = wk;  dst = wkb; }
    else                  { g -= 1638400; src = wv;  dst = wvb; }
    const float4 f0 = *reinterpret_cast<const float4*>(src + (size_t)g * 8);
    const float4 f1 = *reinterpret_cast<const float4*>(src + (size_t)g * 8 + 4);
    bf16x8 v;
    v[0]=(bf16)f0.x; v[1]=(bf16)f0.y; v[2]=(bf16)f0.z; v[3]=(bf16)f0.w;
    v[4]=(bf16)f1.x; v[5]=(bf16)f1.y; v[6]=(bf16)f1.z; v[7]=(bf16)f1.w;
    *reinterpret_cast<bf16x8*>(dst + (size_t)g * 8) = v;
}

// ---------------- Projection GEMMs, m97 structure (R10-identical) --------------------------
// 128x128 tile, BK=32, 256 threads (4 waves 2x2), dbuf LDS via global_load_lds (1KB/instr).
// KV=false: Q row-major. KV=true: K row-major + V t-tiled Vtg[b][t>>5][e][t&31].
template<bool KV>
__global__ __launch_bounds__(256, 2) void proj_kernel(const bf16* __restrict__ A,
    const bf16* __restrict__ W0, const float* __restrict__ b0, bf16* __restrict__ out0,
    const bf16* __restrict__ W1, const float* __restrict__ b1, bf16* __restrict__ out1)
{
    __shared__ __align__(16) bf16 As[2][128][32];
    __shared__ __align__(16) bf16 W0s[2][128][32];
    __shared__ __align__(16) bf16 W1s[2][128][32];   // eliminated by compiler when !KV

    const int tid  = threadIdx.x;
    const int w    = tid >> 6, lane = tid & 63, quad = lane >> 4, l15 = lane & 15;
    const int wr   = w >> 1, wc = w & 1;
    const int n0   = blockIdx.x * 128;
    const int m0   = blockIdx.y * 128;

    const int lrow = lane >> 2;
    const int scol = ((lane & 3) ^ (lrow & 3)) * 8;
    const bf16* aSrc  = A  + (size_t)(m0 + lrow) * DM + scol;
    const bf16* wSrc0 = W0 + (size_t)(n0 + lrow) * DM + scol;
    const bf16* wSrc1 = KV ? (W1 + (size_t)(n0 + lrow) * DM + scol) : nullptr;

    auto stage = [&](int p, int kk) {
#pragma unroll
        for (int j = 0; j < 2; j++) {
            const int seg = 2 * w + j;                  // 8 segments of 16 rows
            gload_lds16(aSrc  + (size_t)(16 * seg) * DM + kk, &As[p][16 * seg][0]);
            gload_lds16(wSrc0 + (size_t)(16 * seg) * DM + kk, &W0s[p][16 * seg][0]);
            if constexpr (KV)
                gload_lds16(wSrc1 + (size_t)(16 * seg) * DM + kk, &W1s[p][16 * seg][0]);
        }
    };

    f32x4 acc0[4][4] = {}, acc1[4][4] = {};
    const int sx = (l15 & 3);

    stage(0, 0);
    __syncthreads();

    for (int step = 0; step < 16; step++) {
        const int p = step & 1;
        if (step < 15) stage(p ^ 1, (step + 1) * 32);

        bf16x8 af[4];
#pragma unroll
        for (int mt = 0; mt < 4; mt++)
            af[mt] = *reinterpret_cast<const bf16x8*>(
                &As[p][64*wr + 16*mt + l15][(quad ^ sx) * 8]);
#pragma unroll
        for (int nt = 0; nt < 4; nt++) {
            bf16x8 w0f = *reinterpret_cast<const bf16x8*>(
                &W0s[p][64*wc + 16*nt + l15][(quad ^ sx) * 8]);
#pragma unroll
            for (int mt = 0; mt < 4; mt++)
                acc0[mt][nt] = __builtin_amdgcn_mfma_f32_16x16x32_bf16(af[mt], w0f, acc0[mt][nt], 0, 0, 0);
            if constexpr (KV) {
                bf16x8 w1f = *reinterpret_cast<const bf16x8*>(
                    &W1s[p][64*wc + 16*nt + l15][(quad ^ sx) * 8]);
#pragma unroll
                for (int mt = 0; mt < 4; mt++)
                    acc1[mt][nt] = __builtin_amdgcn_mfma_f32_16x16x32_bf16(af[mt], w1f, acc1[mt][nt], 0, 0, 0);
            }
        }
        __syncthreads();
    }

#pragma unroll
    for (int mt = 0; mt < 4; mt++)
#pragma unroll
        for (int nt = 0; nt < 4; nt++) {
            const int coll = 64*wc + 16*nt + l15;
            const int rowl = 64*wr + 16*mt + quad*4;
            {
                const float bv = b0[n0 + coll];
                f32x4 c = acc0[mt][nt];
#pragma unroll
                for (int r = 0; r < 4; r++)
                    out0[(size_t)(m0 + rowl + r) * DM + n0 + coll] = (bf16)(c[r] + bv);
            }
            if constexpr (KV) {
                const float bv = b1[n0 + coll];
                f32x4 c = acc1[mt][nt];
                const int gr = m0 + rowl;
                const int bidx = gr >> 12, t = gr & 4095;
                const int e = n0 + coll;
                union { uint2 u; bf16 h[4]; } pk;
#pragma unroll
                for (int r = 0; r < 4; r++) pk.h[r] = (bf16)(c[r] + bv);
                *reinterpret_cast<uint2*>(out1 +
                    ((((size_t)(bidx*128 + (t >> 5)) * DM + e) << 5) + (t & 31))) = pk.u;
            }
        }
}

// ---------------- Fused attention: single-barrier pipeline (QK(t) || PV(t-1)) --------------
// 512 threads / 8 waves (R9 geometry), 1 block/CU, grid 256 = 1 round.
// QK: wave (qb=w>>1, cb0=2*(w&1)): S[16qb..+16][16cb0..+32]; A = Q regs af[16], B = Kt LDS.
// PV: wave w: O[64 q][64 e cols 64w..]; A = Ps[(t-1)&1] LDS, B = V regs (t-tiled bursts).
// Per tile: ONE lgkm-only barrier. Ps double-buffered. DMA ordered before vf (vmcnt FIFO).
__global__ __launch_bounds__(512, 2) void attn_kernel(const bf16* __restrict__ Qb,
                                                      const bf16* __restrict__ Kb,
                                                      const bf16* __restrict__ Vtg,
                                                      float* __restrict__ Op,
                                                      float* __restrict__ lp)
{
    __shared__ __align__(16) bf16 Kt[2][64][512];   // 131,072 B; 4-bit XOR swizzle (src-side)
    __shared__ __align__(16) bf16 Ps[2][64][80];    //  20,480 B; double-buffered
    __shared__ float lred[64];

    const int tid  = threadIdx.x;
    const int w    = tid >> 6, lane = tid & 63, quad = lane >> 4, l15 = lane & 15;
    const int qb   = w >> 1;                 // QK q-row block 0..3
    const int cb0  = (w & 1) * 2;            // QK kv col blocks {cb0, cb0+1}

    // XCD-swizzle: 8 (b,z) combos map 1:1 onto 8 XCDs.
    const int id = blockIdx.x;               // 256 blocks
    const int combo = id & 7, qblk = id >> 3;
    const int b = combo & 3, z = combo >> 2;
    const int q0 = qblk * 64;
    const int NT = 32, tb = z * 2048;        // 32 tiles of 64 kv rows

    // ---- Q A-fragments into registers (once; 64 VGPR) ----
    bf16x8 af[16];
    {
        const bf16* qsrc = Qb + (size_t)(b*2048 + q0 + 16*qb + l15) * DM + quad*8;
#pragma unroll
        for (int k4 = 0; k4 < 16; k4++) af[k4] = *reinterpret_cast<const bf16x8*>(qsrc + k4*32);
    }
    if (tid < 64) lred[tid] = 0.f;

    const bf16* kbase = Kb + (size_t)(b*4096 + tb) * DM;
    // ---- stage K tile 0 (1 contiguous 1KB row/instr; source lane 4-bit XOR) ----
#pragma unroll
    for (int i = 0; i < 8; i++) {
        const int row = w + 8*i;             // row & 7 == w
        gload_lds16(kbase + (size_t)row * DM + ((lane ^ (row & 15)) * 8), &Kt[0][row][0]);
    }
    __syncthreads();                          // drains DMA(0), publishes lred

    f32x4 oacc[4][4] = {};
    float lsum[2][4] = {};
    const float kexp = 1.44269504088896f * 0.044194173824159216f;  // log2(e)/sqrt(512)
    const int sxor = l15 << 4;                // read-side 4-bit XOR (rows read have row&15==l15)

    for (int t = 0; t <= NT; t++) {
        const int buf = t & 1;

        // (1) DMA next K tile FIRST (vmcnt FIFO: later vf-wait implies this landed)
        if (t + 1 < NT) {
            const bf16* ksrc = kbase + (size_t)(t + 1) * 64 * DM;
#pragma unroll
            for (int i = 0; i < 8; i++) {
                const int row = w + 8*i;
                gload_lds16(ksrc + (size_t)row * DM + ((lane ^ (row & 15)) * 8), &Kt[buf ^ 1][row][0]);
            }
        }

        // (2) V fragments for tile t-1 (consumed by PV below; in flight during QK)
        bf16x8 vf[4][2];
        if (t >= 1) {
#pragma unroll
            for (int ks = 0; ks < 2; ks++) {
                const size_t tblk = (size_t)(b*128 + z*64 + (t-1)*2 + ks) * DM;
#pragma unroll
                for (int nt = 0; nt < 4; nt++)
                    vf[nt][ks] = *reinterpret_cast<const bf16x8*>(
                        Vtg + ((tblk + 64*w + 16*nt + l15) << 5) + quad*8);
            }
        }

        // (3) QK(t): S[16qb..+16][16(cb0..cb0+2)], A regs x B LDS; exp -> Ps[buf]
        if (t < NT) {
            f32x4 sacc[2] = {};
            const char* krowA = (const char*)&Kt[buf][16*cb0 + l15][0];
            const char* krowB = (const char*)&Kt[buf][16*cb0 + 16 + l15][0];
#pragma unroll
            for (int k4 = 0; k4 < 16; k4++) {
                const int off = (k4*64 + quad*16) ^ sxor;
                bf16x8 k0 = *reinterpret_cast<const bf16x8*>(krowA + off);
                bf16x8 k1 = *reinterpret_cast<const bf16x8*>(krowB + off);
                sacc[0] = __builtin_amdgcn_mfma_f32_16x16x32_bf16(af[k4], k0, sacc[0], 0, 0, 0);
                sacc[1] = __builtin_amdgcn_mfma_f32_16x16x32_bf16(af[k4], k1, sacc[1], 0, 0, 0);
            }
#pragma unroll
            for (int s = 0; s < 2; s++)
#pragma unroll
                for (int r = 0; r < 4; r++) {
                    const float p = exp2f(sacc[s][r] * kexp);
                    lsum[s][r] += p;
                    Ps[buf][16*qb + quad*4 + r][16*(cb0 + s) + l15] = (bf16)p;
                }
        }

        // (4) PV(t-1): O[64][64w..+64] += P[64][64] * V[64][...], A = Ps[buf^1], B = vf
        if (t >= 1) {
#pragma unroll
            for (int ks = 0; ks < 2; ks++) {
                bf16x8 ap[4];
#pragma unroll
                for (int mt = 0; mt < 4; mt++)
                    ap[mt] = *reinterpret_cast<const bf16x8*>(&Ps[buf ^ 1][16*mt + l15][ks*32 + quad*8]);
#pragma unroll
                for (int nt = 0; nt < 4; nt++)
#pragma unroll
                    for (int mt = 0; mt < 4; mt++)
                        oacc[mt][nt] = __builtin_amdgcn_mfma_f32_16x16x32_bf16(ap[mt], vf[nt][ks], oacc[mt][nt], 0, 0, 0);
            }
        }

        // (5) single barrier: Ps[buf] published; Ps[buf^1] free for overwrite next iter.
        if (t == 0) asm volatile("s_waitcnt vmcnt(0)" ::: "memory");  // no PV drained DMA(1)
        asm volatile("s_waitcnt lgkmcnt(0)" ::: "memory");
        __builtin_amdgcn_s_barrier();
        __builtin_amdgcn_sched_barrier(0);
    }

    // ---- epilogue: l reduction + O partial write ----
#pragma unroll
    for (int r = 0; r < 4; r++)
        atomicAdd(&lred[16*qb + quad*4 + r], lsum[0][r] + lsum[1][r]);
    __syncthreads();

    if (tid < 64) lp[(size_t)z * 8192 + b * 2048 + q0 + tid] = lred[tid];
#pragma unroll
    for (int mt = 0; mt < 4; mt++)
#pragma unroll
        for (int r = 0; r < 4; r++) {
            const int row = 16*mt + quad*4 + r;
            float* obase = Op + ((size_t)z * 8192 + b * 2048 + q0 + row) * DM;
#pragma unroll
            for (int nt = 0; nt < 4; nt++)
                obase[64*w + 16*nt + l15] = oacc[mt][nt][r];
        }
}

// ---------------- Combine split partials: out = sum_z Op[z] / sum_z l[z] -------------------
__global__ __launch_bounds__(256) void reduce_kernel(const float* __restrict__ Op,
                                                     const float* __restrict__ lp,
                                                     float* __restrict__ out)
{
    const int g = blockIdx.x * 256 + threadIdx.x;    // 1,048,576 threads x float4
    const size_t e = (size_t)g * 4;
    const int row = g >> 7;
    float4 o = *reinterpret_cast<const float4*>(Op + e);
    float4 a = *reinterpret_cast<const float4*>(Op + 4194304 + e);
    const float l = lp[row] + lp[8192 + row];
    const float linv = 1.0f / l;
    o.x = (o.x + a.x) * linv;
    o.y = (o.y + a.y) * linv;
    o.z = (o.z + a.z) * linv;
    o.w = (o.w + a.w) * linv;
    *reinterpret_cast<float4*>(out + e) = o;
}

extern "C" void kernel_launch(void* const* d_in, const int* in_sizes, int n_in,
                              void* d_out, int out_size, void* d_ws, size_t ws_size,
                              hipStream_t stream)
{
    const float* x   = (const float*)d_in[0];
    const float* enc = (const float*)d_in[1];
    const float* wq  = (const float*)d_in[2];
    const float* bq  = (const float*)d_in[3];
    const float* wk  = (const float*)d_in[4];
    const float* bk  = (const float*)d_in[5];
    const float* wv  = (const float*)d_in[6];
    const float* bv  = (const float*)d_in[7];
    float* out = (float*)d_out;

    char* ws = (char*)d_ws;
    bf16*  Qb   = (bf16*)ws;
    bf16*  Kb   = (bf16*)(ws + 8388608);
    bf16*  Vtg  = (bf16*)(ws + 25165824);
    bf16*  xb   = (bf16*)(ws + 41943040);
    bf16*  encb = (bf16*)(ws + 50331648);
    bf16*  wqb  = (bf16*)(ws + 67108864);
    bf16*  wkb  = (bf16*)(ws + 67633152);
    bf16*  wvb  = (bf16*)(ws + 68157440);
    float* Op   = (float*)(ws + 41943040);          // overlaps xb/encb/w*b (phase 2)
    float* lp   = (float*)(ws + 41943040 + 2ull * 16777216);

    // prepass: fp32 -> bf16, single launch
    hipLaunchKernelGGL(cvt_all_kernel, dim3(6528), dim3(256), 0, stream,
                       x, xb, enc, encb, wq, wqb, wk, wkb, wv, wvb);

    // projections (m97-structure 128x128 tiles)
    hipLaunchKernelGGL((proj_kernel<false>), dim3(4, 64), dim3(256), 0, stream,
                       xb, wqb, bq, Qb, (const bf16*)nullptr, (const float*)nullptr, (bf16*)nullptr);
    hipLaunchKernelGGL((proj_kernel<true>),  dim3(4, 128), dim3(256), 0, stream,
                       encb, wkb, bk, Kb, wvb, bv, Vtg);

    // attention (256 blocks x 512 threads, 1 block/CU, single-barrier pipeline) + combine
    hipLaunchKernelGGL(attn_kernel, dim3(256), dim3(512), 0, stream, Qb, Kb, Vtg, Op, lp);
    hipLaunchKernelGGL(reduce_kernel, dim3(4096), dim3(256), 0, stream, Op, lp, out);
}